// Round 21
// baseline (368.035 us; speedup 1.0000x reference)
//
#include <hip/hip_runtime.h>

// NucleiGNN fused forward. Live-path ladder: r13 427 -> r15 388 -> r17 358
// -> r18 327 -> r19 285us hot (absmax 0.0332). r20's global_load_lds
// staging CRASHED on first live execution (r11 "validated" it only on the
// dead path) -> re-implement Wo/Wf LDS staging with ORDINARY ld/st:
//   kvq phase: each thread copies 64B of Wo[l] -> wbuf0 (4x bf16x8 loads
//     + 4 ds_writes). Published by B2; used after B3.
//   attention phase: same for Wf[l] -> wbuf1. Published by B3; used after B5.
// No new sync; existing barriers give cross-wave visibility. Wo/Wf dense
// B-frags now come from LDS; the L2 round-trips are moved into phases
// with 8 waves of covering work. Math BIT-IDENTICAL to r19 -> absmax
// must stay 0.03320312 (drift = staging bug).
// Everything else = r19: all matmuls 1-term single-bf16, 6 barriers/layer,
// fused kvq dense, d/exp cache, P in 2KB swizzled slab/wave.
// LDS 88.3 -> 153.8KB (occupancy pinned at 1 WG/CU regardless; r1 ran 154KB).

#define NBATCH 2048
#define NATOM  64
#define NF     128
#define NLAYER 3
#define STR    132   // f32 scratch row stride
#define ASTRB  136   // bf16 row-major tile stride
#define VSTR   72    // vT row stride
#define NTH    512

using bf16x8 = __attribute__((ext_vector_type(8))) __bf16;
using bf16x4 = __attribute__((ext_vector_type(4))) __bf16;
using f32x4  = __attribute__((ext_vector_type(4))) float;

__device__ __forceinline__ float bf2f(unsigned short u) {
    union { unsigned int i; float f; } v; v.i = ((unsigned int)u) << 16; return v.f;
}
__device__ __forceinline__ unsigned short f2bf(float f) {
    union { float ff; unsigned int i; } v; v.ff = f;
    unsigned int x = v.i;
    if ((x & 0x7f800000u) == 0x7f800000u) return (unsigned short)(x >> 16);
    return (unsigned short)((x + 0x7fffu + ((x >> 16) & 1u)) >> 16);
}
__device__ __forceinline__ unsigned short bfbits(float x) {
    union { __bf16 b; unsigned short u; } v; v.b = (__bf16)x; return v.u;
}

__device__ __forceinline__ float fast_rcp(float x)  { return __builtin_amdgcn_rcpf(x); }
__device__ __forceinline__ float fast_sqrt(float x) { return __builtin_amdgcn_sqrtf(x); }
__device__ __forceinline__ float fast_exp(float x)  { return __builtin_amdgcn_exp2f(x * 1.4426950408889634f); }

template<bool BF16>
__device__ __forceinline__ float ldT(const void* p, int i) {
    if constexpr (BF16) return bf2f(((const unsigned short*)p)[i]);
    else                return ((const float*)p)[i];
}
template<bool BF16>
__device__ __forceinline__ float4 ld4T(const void* p, int i) {
    if constexpr (BF16) {
        ushort4 v = *(const ushort4*)((const unsigned short*)p + i);
        return make_float4(bf2f(v.x), bf2f(v.y), bf2f(v.z), bf2f(v.w));
    } else {
        return *(const float4*)((const float*)p + i);
    }
}

// LN row statistics; 32 consecutive lanes share a row.
__device__ __forceinline__ void ln_stats(const float (&h)[4][4], float (&mu)[4], float (&rs)[4]) {
    #pragma unroll
    for (int i = 0; i < 4; ++i) {
        float s  = h[i][0] + h[i][1] + h[i][2] + h[i][3];
        float s2 = h[i][0]*h[i][0] + h[i][1]*h[i][1] + h[i][2]*h[i][2] + h[i][3]*h[i][3];
        #pragma unroll
        for (int m = 1; m <= 16; m <<= 1) {
            s  += __shfl_xor(s,  m);
            s2 += __shfl_xor(s2, m);
        }
        float mm = s * (1.f / 128.f);
        float vv = s2 * (1.f / 128.f) - mm * mm;
        mu[i] = mm;
        rs[i] = rsqrtf(fmaxf(vv, 0.f) + 1e-5f);
    }
}

// normalize h with (mu,rs), store single-bf16 into A tile
__device__ __forceinline__ void write_a(const float (&h)[4][4], const float (&mu)[4], const float (&rs)[4],
                                        __bf16* __restrict__ a_hi, int r0, int fq) {
    #pragma unroll
    for (int i = 0; i < 4; ++i) {
        bf16x4 v;
        #pragma unroll
        for (int jj = 0; jj < 4; ++jj)
            v[jj] = (__bf16)((h[i][jj] - mu[i]) * rs[i]);
        *(bf16x4*)&a_hi[(r0 + i) * ASTRB + fq * 4] = v;
    }
}

// Ordinary-ld/st staging: each of 512 threads copies 64B (4x16B).
// Published to other waves by the NEXT __syncthreads.
__device__ __forceinline__ void stage_w32(const __bf16* __restrict__ g,
                                          __bf16* __restrict__ buf, int t)
{
    const bf16x8* src = (const bf16x8*)g + t * 4;
    bf16x8 w0 = src[0], w1 = src[1], w2 = src[2], w3 = src[3];
    bf16x8* dst = (bf16x8*)buf + t * 4;
    dst[0] = w0; dst[1] = w1; dst[2] = w2; dst[3] = w3;
}

// Fused k/v/q dense, 1-term each: A-frags loaded ONCE per kc, feed 6 chains.
__device__ __forceinline__ void mfma_dense3(const __bf16* __restrict__ a_hi,
                                            const __bf16* __restrict__ bk,
                                            const __bf16* __restrict__ bv,
                                            const __bf16* __restrict__ bq,
                                            f32x4 (&kacc)[2][2], f32x4 (&vacc)[2][2],
                                            f32x4 (&qacc)[2][2], int lane, int wave)
{
    const int R0  = (wave >> 2) << 5;
    const int Cq2 = (wave & 3) << 1;
    const int c = lane & 15, g = lane >> 4;
    #pragma unroll
    for (int t2 = 0; t2 < 2; ++t2)
        #pragma unroll
        for (int j = 0; j < 2; ++j) {
            kacc[t2][j] = (f32x4){0.f, 0.f, 0.f, 0.f};
            vacc[t2][j] = (f32x4){0.f, 0.f, 0.f, 0.f};
            qacc[t2][j] = (f32x4){0.f, 0.f, 0.f, 0.f};
        }
    #pragma unroll
    for (int kc = 0; kc < 4; ++kc) {
        const int ao = kc * 32 + (g << 3);
        bf16x8 a0h = *(const bf16x8*)&a_hi[(R0 + c) * ASTRB + ao];
        bf16x8 a1h = *(const bf16x8*)&a_hi[(R0 + 16 + c) * ASTRB + ao];
        #pragma unroll
        for (int j = 0; j < 2; ++j) {
            const int bi = ((((kc << 3) + Cq2 + j) << 6) + lane) << 3;
            bf16x8 wk_ = *(const bf16x8*)&bk[bi];
            bf16x8 wv_ = *(const bf16x8*)&bv[bi];
            bf16x8 wq_ = *(const bf16x8*)&bq[bi];
            kacc[0][j] = __builtin_amdgcn_mfma_f32_16x16x32_bf16(a0h, wk_, kacc[0][j], 0, 0, 0);
            vacc[0][j] = __builtin_amdgcn_mfma_f32_16x16x32_bf16(a0h, wv_, vacc[0][j], 0, 0, 0);
            qacc[0][j] = __builtin_amdgcn_mfma_f32_16x16x32_bf16(a0h, wq_, qacc[0][j], 0, 0, 0);
            kacc[1][j] = __builtin_amdgcn_mfma_f32_16x16x32_bf16(a1h, wk_, kacc[1][j], 0, 0, 0);
            vacc[1][j] = __builtin_amdgcn_mfma_f32_16x16x32_bf16(a1h, wv_, vacc[1][j], 0, 0, 0);
            qacc[1][j] = __builtin_amdgcn_mfma_f32_16x16x32_bf16(a1h, wq_, qacc[1][j], 0, 0, 0);
        }
    }
}

// Dense [64,128]x[128,128]: 2x2 tiles/wave, 1-term single-bf16 (B in LDS or L2).
__device__ __forceinline__ void mfma_dense(const __bf16* __restrict__ a_hi,
                                           const __bf16* __restrict__ bp,
                                           f32x4 (&acc)[2][2], int lane, int wave)
{
    const int R0  = (wave >> 2) << 5;
    const int Cq2 = (wave & 3) << 1;
    const int c = lane & 15, g = lane >> 4;
    #pragma unroll
    for (int t2 = 0; t2 < 2; ++t2)
        #pragma unroll
        for (int j = 0; j < 2; ++j)
            acc[t2][j] = (f32x4){0.f, 0.f, 0.f, 0.f};
    #pragma unroll
    for (int kc = 0; kc < 4; ++kc) {
        const int ao = kc * 32 + (g << 3);
        bf16x8 a0h = *(const bf16x8*)&a_hi[(R0 + c) * ASTRB + ao];
        bf16x8 a1h = *(const bf16x8*)&a_hi[(R0 + 16 + c) * ASTRB + ao];
        #pragma unroll
        for (int j = 0; j < 2; ++j) {
            const int bi = ((((kc << 3) + Cq2 + j) << 6) + lane) << 3;
            bf16x8 bh = *(const bf16x8*)&bp[bi];
            acc[0][j] = __builtin_amdgcn_mfma_f32_16x16x32_bf16(a0h, bh, acc[0][j], 0, 0, 0);
            acc[1][j] = __builtin_amdgcn_mfma_f32_16x16x32_bf16(a1h, bh, acc[1][j], 0, 0, 0);
        }
    }
}

// C (2x2 tiles) -> single-bf16 row-major [64][ASTRB]
__device__ __forceinline__ void writeC_rm(const f32x4 (&acc)[2][2],
                                          __bf16* __restrict__ hi, int lane, int wave)
{
    const int R0 = (wave >> 2) << 5;
    const int C0 = (wave & 3) << 5;
    const int c = lane & 15, g4 = (lane >> 4) << 2;
    #pragma unroll
    for (int t2 = 0; t2 < 2; ++t2)
    #pragma unroll
    for (int j = 0; j < 2; ++j)
    #pragma unroll
    for (int r = 0; r < 4; ++r)
        hi[(R0 + 16*t2 + g4 + r) * ASTRB + C0 + 16*j + c] = (__bf16)acc[t2][j][r];
}

// C (2x2 tiles) -> single-bf16 TRANSPOSED vT[d][m]
__device__ __forceinline__ void writeC_vt(const f32x4 (&acc)[2][2],
                                          __bf16* __restrict__ hi, int lane, int wave)
{
    const int R0 = (wave >> 2) << 5;   // m rows
    const int C0 = (wave & 3) << 5;    // d cols
    const int c = lane & 15, g4 = (lane >> 4) << 2;
    #pragma unroll
    for (int t2 = 0; t2 < 2; ++t2)
    #pragma unroll
    for (int j = 0; j < 2; ++j)
    #pragma unroll
    for (int r = 0; r < 4; ++r) {
        int m = R0 + 16*t2 + g4 + r, d = C0 + 16*j + c;
        hi[d * VSTR + m] = (__bf16)acc[t2][j][r];
    }
}

// C (2x2 tiles) -> f32 scratch [64][STR]
__device__ __forceinline__ void writeC_f32(const f32x4 (&acc)[2][2],
                                           float* __restrict__ dst, int lane, int wave)
{
    const int R0 = (wave >> 2) << 5;
    const int C0 = (wave & 3) << 5;
    const int c = lane & 15, g4 = (lane >> 4) << 2;
    #pragma unroll
    for (int t2 = 0; t2 < 2; ++t2)
    #pragma unroll
    for (int j = 0; j < 2; ++j)
    #pragma unroll
    for (int r = 0; r < 4; ++r)
        dst[(R0 + 16*t2 + g4 + r) * STR + C0 + 16*j + c] = acc[t2][j][r];
}

// Pre-split weights into bf16 hi/lo, packed in MFMA B-fragment order.
// Slot layout: wpack[(kind*3 + l)*32768]: [0,16384)=hi frags, [16384,32768)=lo.
// (lo plane kept for layout compatibility; unused by the kernel now.)
template<bool BF16>
__global__ __launch_bounds__(256)
void prep_w(const void* __restrict__ Wq, const void* __restrict__ Wk,
            const void* __restrict__ Wv, const void* __restrict__ Wo,
            const void* __restrict__ Wf, unsigned short* __restrict__ wpack)
{
    {
        const unsigned int* w = (const unsigned int*)Wq;
        bool isbf = true;
        #pragma unroll
        for (int i = 0; i < 16; ++i) {
            unsigned int e = (w[i] >> 7) & 0xFFu;
            isbf = isbf && (e >= 0x60u && e <= 0x7Eu);
        }
        if (isbf != BF16) return;
    }
    const int mat  = blockIdx.x;            // 0..14 = kind*3 + l
    const int kind = mat / 3, l = mat % 3;
    const void* src = (kind == 0) ? Wq : (kind == 1) ? Wk : (kind == 2) ? Wv
                    : (kind == 3) ? Wo : Wf;
    unsigned short* dh = wpack + (size_t)mat * 32768;
    unsigned short* dl = dh + 16384;
    for (int f = threadIdx.x; f < 16384; f += 256) {
        int e    = f & 7;
        int lane = (f >> 3) & 63;
        int tj   = (f >> 9) & 7;
        int kc   = f >> 12;
        int row  = kc * 32 + ((lane >> 4) << 3) + e;
        int col  = tj * 16 + (lane & 15);
        float x  = ldT<BF16>(src, (l * NF + row) * NF + col);
        unsigned short hi = f2bf(x);
        unsigned short lo = f2bf(x - bf2f(hi));
        dh[f] = hi; dl[f] = lo;
    }
}

// a 8704 + q 8704 + k 8704 + vt 9216 + P 8192 = 43520 bf16
// + wbuf0/wbuf1 2x16384 bf16 + tail
static constexpr size_t SMEM_BYTES =
    (size_t)(43520 + 2 * 16384) * 2 + (256 + 48) * 4 + 16;   // 153808 B (r1 ran 154064)

template<bool BF16>
__global__ __launch_bounds__(NTH, 1)
void gnn_fused(const void* __restrict__ coords,
               const int* __restrict__ species,
               const unsigned char* __restrict__ maskraw,
               const void* __restrict__ embed,
               const void* __restrict__ Wq,          // dtype signature only
               const void* __restrict__ We,
               const void* __restrict__ bfb,
               const unsigned short* __restrict__ wpack,
               void* __restrict__ out)
{
    // ---- dtype signature check (block-uniform; wrong instantiation exits) ----
    {
        const unsigned int* w = (const unsigned int*)Wq;
        bool isbf = true;
        #pragma unroll
        for (int i = 0; i < 16; ++i) {
            unsigned int e = (w[i] >> 7) & 0xFFu;
            isbf = isbf && (e >= 0x60u && e <= 0x7Eu);
        }
        if (isbf != BF16) return;
    }

    extern __shared__ __bf16 sm[];
    __bf16* a_hi  = sm;                                 // [64][136] hn/msg
    __bf16* q_hi  = sm + 8704;                          // [64][136] q
    __bf16* k_hi  = sm + 17408;                         // [64][136] k
    __bf16* vt_hi = sm + 26112;                         // [128][72] v transposed
    __bf16* p_hi  = sm + 35328;                         // 8 waves x 2KB swz
    __bf16* wbuf0 = sm + 43520;                         // Wo[l] staging (32KB)
    __bf16* wbuf1 = sm + 59904;                         // Wf[l] staging (32KB)
    float*  scratch = (float*)k_hi;                     // spans k+vt: 35840B >= 33792B
    float*  tailf = (float*)(sm + 76288);
    float*  cs   = tailf;                               // 64*4 coords
    float*  wel  = cs + 256;                            // 48 We (f32)
    int*    lenp = (int*)(wel + 48);

    const int t    = threadIdx.x;
    const int b    = blockIdx.x;
    const int fq   = t & 31;
    const int r0   = (t >> 5) * 4;
    const int lane = t & 63;
    const int wave = t >> 6;
    const int c    = lane & 15;
    const int g    = lane >> 4;
    const int g4   = g << 2;
    const int hd   = wave >> 2;          // attention head of this wave
    const int wb   = (wave & 3) << 4;    // attention row base of this wave

    // ---- init: coords, We, mask length ----
    if (t < 64) {
        cs[t * 4 + 0] = ldT<BF16>(coords, (b * NATOM + t) * 3 + 0);
        cs[t * 4 + 1] = ldT<BF16>(coords, (b * NATOM + t) * 3 + 1);
        cs[t * 4 + 2] = ldT<BF16>(coords, (b * NATOM + t) * 3 + 2);
    }
    if (t >= 64 && t < 64 + 42) wel[t - 64] = ldT<BF16>(We, t - 64);
    if (t < 64) {
        unsigned int w0 = *(const unsigned int*)maskraw;
        bool f;
        if (w0 == 1u)               f = ((const int*)maskraw)[b * NATOM + t] != 0;
        else if (w0 == 0x01010101u) f = maskraw[b * NATOM + t] != 0;
        else if (w0 == 0x3F800000u) f = ((const float*)maskraw)[b * NATOM + t] != 0.f;
        else                        f = ((const unsigned short*)maskraw)[b * NATOM + t] != 0;
        unsigned long long bal = __ballot(f);
        if (t == 0) *lenp = (int)__popcll(bal);
    }

    // ---- h0 = embed[species-1] ----
    float h[4][4];
    #pragma unroll
    for (int i = 0; i < 4; ++i) {
        int sp = species[b * NATOM + r0 + i];
        float4 ev = ld4T<BF16>(embed, (sp - 1) * NF + fq * 4);
        h[i][0] = ev.x; h[i][1] = ev.y; h[i][2] = ev.z; h[i][3] = ev.w;
    }
    __syncthreads();
    const int len = *lenp;
    #pragma unroll
    for (int i = 0; i < 4; ++i)
        if (r0 + i >= len) { h[i][0]=0.f; h[i][1]=0.f; h[i][2]=0.f; h[i][3]=0.f; }

    // ---- layer-invariant edge cache: d and exp(-d) per pair (32 regs) ----
    float pdc[4][4], pec[4][4];
    {
        float cnx[4], cny[4], cnz[4];
        #pragma unroll
        for (int r = 0; r < 4; ++r) {
            int n = wb + g4 + r;
            cnx[r] = cs[n*4]; cny[r] = cs[n*4+1]; cnz[r] = cs[n*4+2];
        }
        #pragma unroll
        for (int jt = 0; jt < 4; ++jt) {
            int mc = jt * 16 + c;
            float cmx = cs[mc*4], cmy = cs[mc*4+1], cmz = cs[mc*4+2];
            #pragma unroll
            for (int r = 0; r < 4; ++r) {
                float dx = cnx[r]-cmx, dy = cny[r]-cmy, dz = cnz[r]-cmz;
                float d = fast_sqrt(dx*dx + dy*dy + dz*dz + 1e-12f);
                pdc[jt][r] = d;
                pec[jt][r] = fast_exp(-d);
            }
        }
    }

    float mu[4], rs[4];
    for (int l = 0; l < NLAYER; ++l) {
        // hn = LN(h) -> single-bf16 A tile
        ln_stats(h, mu, rs);
        write_a(h, mu, rs, a_hi, r0, fq);
        __syncthreads();                                        // B1: a ready

        // stage Wo[l] -> wbuf0 (ordinary ld/st; wbuf0 dead since prev B4;
        // ds_writes drained + published by B2)
        stage_w32((const __bf16*)wpack + (size_t)(9 + l) * 32768, wbuf0, t);

        // k, vT, q: fused dense, A-frags shared, 1-term each (B from L2)
        {
            f32x4 kacc[2][2], vacc[2][2], qacc[2][2];
            mfma_dense3(a_hi,
                        (const __bf16*)wpack + (size_t)(3 + l) * 32768,
                        (const __bf16*)wpack + (size_t)(6 + l) * 32768,
                        (const __bf16*)wpack + (size_t)(0 + l) * 32768,
                        kacc, vacc, qacc, lane, wave);
            writeC_rm(kacc, k_hi, lane, wave);
            writeC_vt(vacc, vt_hi, lane, wave);
            writeC_rm(qacc, q_hi, lane, wave);
        }
        __syncthreads();                                        // B2: k/vT/q + wbuf0 visible

        // stage Wf[l] -> wbuf1 (wbuf1 dead since prev B6; published by B3)
        stage_w32((const __bf16*)wpack + (size_t)(12 + l) * 32768, wbuf1, t);

        // ---- logits = (q @ k^T)/8 + bias (NT: k row-major IS B-frag), 1-term ----
        f32x4 lacc[4];
        #pragma unroll
        for (int jt = 0; jt < 4; ++jt) lacc[jt] = (f32x4){0.f,0.f,0.f,0.f};
        #pragma unroll
        for (int kc = 0; kc < 2; ++kc) {
            const int qo = (wb + c) * ASTRB + hd * 64 + kc * 32 + (g << 3);
            bf16x8 qh = *(const bf16x8*)&q_hi[qo];
            #pragma unroll
            for (int jt = 0; jt < 4; ++jt) {
                const int ko = (jt * 16 + c) * ASTRB + hd * 64 + kc * 32 + (g << 3);
                bf16x8 kh = *(const bf16x8*)&k_hi[ko];
                lacc[jt] = __builtin_amdgcn_mfma_f32_16x16x32_bf16(qh, kh, lacc[jt], 0, 0, 0);
            }
        }

        // ---- edge bias (cached d/exp) + masked softmax ----
        float we_[7];
        #pragma unroll
        for (int e = 0; e < 7; ++e) we_[e] = wel[l * 14 + e * 2 + hd];
        float cnx[4], cny[4], cnz[4];
        #pragma unroll
        for (int r = 0; r < 4; ++r) {
            int n = wb + g4 + r;
            cnx[r] = cs[n*4]; cny[r] = cs[n*4+1]; cnz[r] = cs[n*4+2];
        }
        float lg[4][4];
        #pragma unroll
        for (int jt = 0; jt < 4; ++jt) {
            int mc = jt * 16 + c;
            float cmx = cs[mc*4], cmy = cs[mc*4+1], cmz = cs[mc*4+2];
            #pragma unroll
            for (int r = 0; r < 4; ++r) {
                float dx = cnx[r]-cmx, dy = cny[r]-cmy, dz = cnz[r]-cmz;
                float et = pec[jt][r];
                float s1 = fast_rcp(1.f + 7.38905609893065f   * et);
                float s2 = fast_rcp(1.f + 54.598150033144236f * et);
                float s3 = fast_rcp(1.f + 403.4287934927351f  * et);
                lg[jt][r] = lacc[jt][r] * 0.125f
                          + dx*we_[0] + dy*we_[1] + dz*we_[2]
                          + pdc[jt][r]*we_[3]
                          + s1*we_[4] + s2*we_[5] + s3*we_[6];
            }
        }
        float mx[4] = {-3e38f, -3e38f, -3e38f, -3e38f};
        #pragma unroll
        for (int jt = 0; jt < 4; ++jt)
            if (jt * 16 + c < len) {
                #pragma unroll
                for (int r = 0; r < 4; ++r) mx[r] = fmaxf(mx[r], lg[jt][r]);
            }
        #pragma unroll
        for (int r = 0; r < 4; ++r) {
            mx[r] = fmaxf(mx[r], __shfl_xor(mx[r], 1));
            mx[r] = fmaxf(mx[r], __shfl_xor(mx[r], 2));
            mx[r] = fmaxf(mx[r], __shfl_xor(mx[r], 4));
            mx[r] = fmaxf(mx[r], __shfl_xor(mx[r], 8));
        }
        float sv[4] = {0.f, 0.f, 0.f, 0.f};
        #pragma unroll
        for (int jt = 0; jt < 4; ++jt) {
            bool vm = (jt * 16 + c) < len;
            #pragma unroll
            for (int r = 0; r < 4; ++r) {
                float e = vm ? fast_exp(lg[jt][r] - mx[r]) : 0.f;
                lg[jt][r] = e; sv[r] += e;
            }
        }
        #pragma unroll
        for (int r = 0; r < 4; ++r) {
            sv[r] += __shfl_xor(sv[r], 1);
            sv[r] += __shfl_xor(sv[r], 2);
            sv[r] += __shfl_xor(sv[r], 4);
            sv[r] += __shfl_xor(sv[r], 8);
        }
        float inv[4];
        #pragma unroll
        for (int r = 0; r < 4; ++r)
            inv[r] = (wb + g4 + r < len) ? fast_rcp(sv[r]) : 0.f;

        // ---- P stage: single-bf16, own 2KB swizzled slab per wave ----
        // elem (x=0..15 q-row, mm=0..63 k-idx): byte = x*128 + ((mm*2) ^ ((x&7)<<4))
        {
            char* pw = (char*)p_hi + wave * 2048;
            #pragma unroll
            for (int jt = 0; jt < 4; ++jt)
                #pragma unroll
                for (int r = 0; r < 4; ++r) {
                    int x = g4 + r, mm = jt * 16 + c;
                    *(__bf16*)(pw + x * 128 + ((mm * 2) ^ ((x & 7) << 4))) =
                        (__bf16)(lg[jt][r] * inv[r]);
                }
        }
        // no barrier: P write->read is same-wave (lgkmcnt-ordered)

        // ---- msg = P @ V (1-term) ----
        f32x4 macc[4];
        #pragma unroll
        for (int jt = 0; jt < 4; ++jt) macc[jt] = (f32x4){0.f,0.f,0.f,0.f};
        #pragma unroll
        for (int kc = 0; kc < 2; ++kc) {
            const char* pw = (const char*)p_hi + wave * 2048;
            const int m0 = kc * 32 + (g << 3);
            bf16x8 ph = *(const bf16x8*)(pw + c * 128 + ((m0 * 2) ^ ((c & 7) << 4)));
            #pragma unroll
            for (int jt = 0; jt < 4; ++jt) {
                const int vo = (hd * 64 + jt * 16 + c) * VSTR + kc * 32 + (g << 3);
                bf16x8 vh = *(const bf16x8*)&vt_hi[vo];
                macc[jt] = __builtin_amdgcn_mfma_f32_16x16x32_bf16(ph, vh, macc[jt], 0, 0, 0);
            }
        }
        // msg -> a-region single-bf16 (a dead: all a-readers finished pre-B2)
        #pragma unroll
        for (int jt = 0; jt < 4; ++jt)
            #pragma unroll
            for (int r = 0; r < 4; ++r) {
                int idx = (wb + g4 + r) * ASTRB + hd * 64 + jt * 16 + c;
                a_hi[idx] = (__bf16)macc[jt][r];
            }
        __syncthreads();                                        // B3: msg + wbuf1 visible

        // h += msg @ Wo (Wo from LDS wbuf0; scratch overlays dead k + vt)
        {
            f32x4 oacc[2][2];
            mfma_dense(a_hi, wbuf0, oacc, lane, wave);
            writeC_f32(oacc, scratch, lane, wave);
        }
        __syncthreads();                                        // B4: scratch visible
        #pragma unroll
        for (int i = 0; i < 4; ++i) {
            float4 ov = *(const float4*)&scratch[(r0 + i) * STR + fq * 4];
            h[i][0] += ov.x; h[i][1] += ov.y; h[i][2] += ov.z; h[i][3] += ov.w;
        }

        // h += tanh(LN(h) @ Wf + bf)  (Wf from LDS wbuf1)
        ln_stats(h, mu, rs);
        write_a(h, mu, rs, a_hi, r0, fq);     // Wo a-reads drained at B4
        __syncthreads();                                        // B5: a ready
        {
            f32x4 facc[2][2];
            mfma_dense(a_hi, wbuf1, facc, lane, wave);
            writeC_f32(facc, scratch, lane, wave);   // h-update scratch reads drained at B5
        }
        __syncthreads();                                        // B6: scratch visible
        {
            float4 bv = ld4T<BF16>(bfb, l * NF + fq * 4);
            #pragma unroll
            for (int i = 0; i < 4; ++i) {
                float z0 = scratch[(r0 + i) * STR + fq * 4 + 0] + bv.x;
                float z1 = scratch[(r0 + i) * STR + fq * 4 + 1] + bv.y;
                float z2 = scratch[(r0 + i) * STR + fq * 4 + 2] + bv.z;
                float z3 = scratch[(r0 + i) * STR + fq * 4 + 3] + bv.w;
                // tanh(z) = 1 - 2/(e^{2z}+1)
                h[i][0] += 1.f - 2.f * fast_rcp(fast_exp(2.f*z0) + 1.f);
                h[i][1] += 1.f - 2.f * fast_rcp(fast_exp(2.f*z1) + 1.f);
                h[i][2] += 1.f - 2.f * fast_rcp(fast_exp(2.f*z2) + 1.f);
                h[i][3] += 1.f - 2.f * fast_rcp(fast_exp(2.f*z3) + 1.f);
            }
        }
        // h *= mask
        #pragma unroll
        for (int i = 0; i < 4; ++i)
            if (r0 + i >= len) { h[i][0]=0.f; h[i][1]=0.f; h[i][2]=0.f; h[i][3]=0.f; }
        // next-layer write_a safe: Wf a-reads drained at B6; tanh reads
        // scratch (k region), not a. Next-layer wbuf0 staging is after next
        // B1 (> this B4, its last read); wbuf1 staging after next B2 (> B6).
    }

    // out = LN(h) in output dtype
    ln_stats(h, mu, rs);
    #pragma unroll
    for (int i = 0; i < 4; ++i) {
        int idx = b * NATOM * NF + (r0 + i) * NF + fq * 4;
        float o0 = (h[i][0]-mu[i])*rs[i], o1 = (h[i][1]-mu[i])*rs[i];
        float o2 = (h[i][2]-mu[i])*rs[i], o3 = (h[i][3]-mu[i])*rs[i];
        if constexpr (BF16) {
            ushort4 o;
            o.x = bfbits(o0); o.y = bfbits(o1); o.z = bfbits(o2); o.w = bfbits(o3);
            *(ushort4*)((unsigned short*)out + idx) = o;
        } else {
            *(float4*)((float*)out + idx) = make_float4(o0, o1, o2, o3);
        }
    }
}

extern "C" void kernel_launch(void* const* d_in, const int* in_sizes, int n_in,
                              void* d_out, int out_size, void* d_ws, size_t ws_size,
                              hipStream_t stream) {
    const void*           coords  = d_in[0];
    const int*            species = (const int*)d_in[1];
    const unsigned char*  maskraw = (const unsigned char*)d_in[2];
    const void*           embed   = d_in[3];
    const void*           Wq      = d_in[4];
    const void*           Wk      = d_in[5];
    const void*           Wv      = d_in[6];
    const void*           Wo      = d_in[7];
    const void*           We      = d_in[8];
    const void*           Wf      = d_in[9];
    const void*           bfb     = d_in[10];

    unsigned short* wpack = (unsigned short*)d_ws;   // 15 * 32768 ushorts = 960 KB

    (void)hipFuncSetAttribute((const void*)gnn_fused<true>,
                              hipFuncAttributeMaxDynamicSharedMemorySize,
                              (int)SMEM_BYTES);
    (void)hipFuncSetAttribute((const void*)gnn_fused<false>,
                              hipFuncAttributeMaxDynamicSharedMemorySize,
                              (int)SMEM_BYTES);

    prep_w<true ><<<dim3(15), dim3(256), 0, stream>>>(Wq, Wk, Wv, Wo, Wf, wpack);
    prep_w<false><<<dim3(15), dim3(256), 0, stream>>>(Wq, Wk, Wv, Wo, Wf, wpack);

    gnn_fused<true ><<<dim3(NBATCH), dim3(NTH), SMEM_BYTES, stream>>>(
        coords, species, maskraw, embed, Wq, We, bfb, wpack, d_out);
    gnn_fused<false><<<dim3(NBATCH), dim3(NTH), SMEM_BYTES, stream>>>(
        coords, species, maskraw, embed, Wq, We, bfb, wpack, d_out);
}

// Round 22
// 358.047 us; speedup vs baseline: 1.0279x; 1.0279x over previous
//
#include <hip/hip_runtime.h>

// NucleiGNN fused forward — FINAL (r19 revert; session optimum).
// Ladder (hot dispatch): r0 2593 -> r1 MFMA-dense 1328 -> r3 MFMA-attn 650
// -> r4 VALU-diet 442 -> r13 lean-LDS 427 -> r15 <64KB 388 -> r17 6-barrier
// 358 -> r18 fused-kvq 327 -> r19 all-1-term 285us (bench 360.4, absmax
// 0.0332 vs threshold 0.0838).
// Closed levers: occupancy HW-pinned at 1 WG/CU (r7/r12/r14/r15 sweep);
// 2-mol fusion spills (r16); global_load_lds crashes live (r20); sync
// LDS weight staging is net-negative (r21: +bank conflicts, bit-identical
// math). Remaining time = serial phase latency of the 18-barrier chain.
// Structure: all matmuls 1-term single-bf16 MFMA (weights pre-packed in
// B-frag order in d_ws); fused k/v/q dense (shared A-frags, 6 chains per
// A-load); 6 barriers/layer (own q/P buffers); d/exp(-d) register cache;
// P in 2KB swizzled slab/wave (same-wave readback, no barrier);
// fast exp/rcp/sqrt; f32 scratch overlays dead k+vt.

#define NBATCH 2048
#define NATOM  64
#define NF     128
#define NLAYER 3
#define STR    132   // f32 scratch row stride
#define ASTRB  136   // bf16 row-major tile stride
#define VSTR   72    // vT row stride
#define NTH    512

using bf16x8 = __attribute__((ext_vector_type(8))) __bf16;
using bf16x4 = __attribute__((ext_vector_type(4))) __bf16;
using f32x4  = __attribute__((ext_vector_type(4))) float;

__device__ __forceinline__ float bf2f(unsigned short u) {
    union { unsigned int i; float f; } v; v.i = ((unsigned int)u) << 16; return v.f;
}
__device__ __forceinline__ unsigned short f2bf(float f) {
    union { float ff; unsigned int i; } v; v.ff = f;
    unsigned int x = v.i;
    if ((x & 0x7f800000u) == 0x7f800000u) return (unsigned short)(x >> 16);
    return (unsigned short)((x + 0x7fffu + ((x >> 16) & 1u)) >> 16);
}
__device__ __forceinline__ unsigned short bfbits(float x) {
    union { __bf16 b; unsigned short u; } v; v.b = (__bf16)x; return v.u;
}

__device__ __forceinline__ float fast_rcp(float x)  { return __builtin_amdgcn_rcpf(x); }
__device__ __forceinline__ float fast_sqrt(float x) { return __builtin_amdgcn_sqrtf(x); }
__device__ __forceinline__ float fast_exp(float x)  { return __builtin_amdgcn_exp2f(x * 1.4426950408889634f); }

template<bool BF16>
__device__ __forceinline__ float ldT(const void* p, int i) {
    if constexpr (BF16) return bf2f(((const unsigned short*)p)[i]);
    else                return ((const float*)p)[i];
}
template<bool BF16>
__device__ __forceinline__ float4 ld4T(const void* p, int i) {
    if constexpr (BF16) {
        ushort4 v = *(const ushort4*)((const unsigned short*)p + i);
        return make_float4(bf2f(v.x), bf2f(v.y), bf2f(v.z), bf2f(v.w));
    } else {
        return *(const float4*)((const float*)p + i);
    }
}

// LN row statistics; 32 consecutive lanes share a row.
__device__ __forceinline__ void ln_stats(const float (&h)[4][4], float (&mu)[4], float (&rs)[4]) {
    #pragma unroll
    for (int i = 0; i < 4; ++i) {
        float s  = h[i][0] + h[i][1] + h[i][2] + h[i][3];
        float s2 = h[i][0]*h[i][0] + h[i][1]*h[i][1] + h[i][2]*h[i][2] + h[i][3]*h[i][3];
        #pragma unroll
        for (int m = 1; m <= 16; m <<= 1) {
            s  += __shfl_xor(s,  m);
            s2 += __shfl_xor(s2, m);
        }
        float mm = s * (1.f / 128.f);
        float vv = s2 * (1.f / 128.f) - mm * mm;
        mu[i] = mm;
        rs[i] = rsqrtf(fmaxf(vv, 0.f) + 1e-5f);
    }
}

// normalize h with (mu,rs), store single-bf16 into A tile
__device__ __forceinline__ void write_a(const float (&h)[4][4], const float (&mu)[4], const float (&rs)[4],
                                        __bf16* __restrict__ a_hi, int r0, int fq) {
    #pragma unroll
    for (int i = 0; i < 4; ++i) {
        bf16x4 v;
        #pragma unroll
        for (int jj = 0; jj < 4; ++jj)
            v[jj] = (__bf16)((h[i][jj] - mu[i]) * rs[i]);
        *(bf16x4*)&a_hi[(r0 + i) * ASTRB + fq * 4] = v;
    }
}

// Fused k/v/q dense, 1-term each: A-frags loaded ONCE per kc, feed 6 chains.
__device__ __forceinline__ void mfma_dense3(const __bf16* __restrict__ a_hi,
                                            const __bf16* __restrict__ bk,
                                            const __bf16* __restrict__ bv,
                                            const __bf16* __restrict__ bq,
                                            f32x4 (&kacc)[2][2], f32x4 (&vacc)[2][2],
                                            f32x4 (&qacc)[2][2], int lane, int wave)
{
    const int R0  = (wave >> 2) << 5;
    const int Cq2 = (wave & 3) << 1;
    const int c = lane & 15, g = lane >> 4;
    #pragma unroll
    for (int t2 = 0; t2 < 2; ++t2)
        #pragma unroll
        for (int j = 0; j < 2; ++j) {
            kacc[t2][j] = (f32x4){0.f, 0.f, 0.f, 0.f};
            vacc[t2][j] = (f32x4){0.f, 0.f, 0.f, 0.f};
            qacc[t2][j] = (f32x4){0.f, 0.f, 0.f, 0.f};
        }
    #pragma unroll
    for (int kc = 0; kc < 4; ++kc) {
        const int ao = kc * 32 + (g << 3);
        bf16x8 a0h = *(const bf16x8*)&a_hi[(R0 + c) * ASTRB + ao];
        bf16x8 a1h = *(const bf16x8*)&a_hi[(R0 + 16 + c) * ASTRB + ao];
        #pragma unroll
        for (int j = 0; j < 2; ++j) {
            const int bi = ((((kc << 3) + Cq2 + j) << 6) + lane) << 3;
            bf16x8 wk_ = *(const bf16x8*)&bk[bi];
            bf16x8 wv_ = *(const bf16x8*)&bv[bi];
            bf16x8 wq_ = *(const bf16x8*)&bq[bi];
            kacc[0][j] = __builtin_amdgcn_mfma_f32_16x16x32_bf16(a0h, wk_, kacc[0][j], 0, 0, 0);
            vacc[0][j] = __builtin_amdgcn_mfma_f32_16x16x32_bf16(a0h, wv_, vacc[0][j], 0, 0, 0);
            qacc[0][j] = __builtin_amdgcn_mfma_f32_16x16x32_bf16(a0h, wq_, qacc[0][j], 0, 0, 0);
            kacc[1][j] = __builtin_amdgcn_mfma_f32_16x16x32_bf16(a1h, wk_, kacc[1][j], 0, 0, 0);
            vacc[1][j] = __builtin_amdgcn_mfma_f32_16x16x32_bf16(a1h, wv_, vacc[1][j], 0, 0, 0);
            qacc[1][j] = __builtin_amdgcn_mfma_f32_16x16x32_bf16(a1h, wq_, qacc[1][j], 0, 0, 0);
        }
    }
}

// Dense [64,128]x[128,128]: 2x2 tiles/wave, 1-term single-bf16.
__device__ __forceinline__ void mfma_dense(const __bf16* __restrict__ a_hi,
                                           const __bf16* __restrict__ bp,
                                           f32x4 (&acc)[2][2], int lane, int wave)
{
    const int R0  = (wave >> 2) << 5;
    const int Cq2 = (wave & 3) << 1;
    const int c = lane & 15, g = lane >> 4;
    #pragma unroll
    for (int t2 = 0; t2 < 2; ++t2)
        #pragma unroll
        for (int j = 0; j < 2; ++j)
            acc[t2][j] = (f32x4){0.f, 0.f, 0.f, 0.f};
    #pragma unroll
    for (int kc = 0; kc < 4; ++kc) {
        const int ao = kc * 32 + (g << 3);
        bf16x8 a0h = *(const bf16x8*)&a_hi[(R0 + c) * ASTRB + ao];
        bf16x8 a1h = *(const bf16x8*)&a_hi[(R0 + 16 + c) * ASTRB + ao];
        #pragma unroll
        for (int j = 0; j < 2; ++j) {
            const int bi = ((((kc << 3) + Cq2 + j) << 6) + lane) << 3;
            bf16x8 bh = *(const bf16x8*)&bp[bi];
            acc[0][j] = __builtin_amdgcn_mfma_f32_16x16x32_bf16(a0h, bh, acc[0][j], 0, 0, 0);
            acc[1][j] = __builtin_amdgcn_mfma_f32_16x16x32_bf16(a1h, bh, acc[1][j], 0, 0, 0);
        }
    }
}

// C (2x2 tiles) -> single-bf16 row-major [64][ASTRB]
__device__ __forceinline__ void writeC_rm(const f32x4 (&acc)[2][2],
                                          __bf16* __restrict__ hi, int lane, int wave)
{
    const int R0 = (wave >> 2) << 5;
    const int C0 = (wave & 3) << 5;
    const int c = lane & 15, g4 = (lane >> 4) << 2;
    #pragma unroll
    for (int t2 = 0; t2 < 2; ++t2)
    #pragma unroll
    for (int j = 0; j < 2; ++j)
    #pragma unroll
    for (int r = 0; r < 4; ++r)
        hi[(R0 + 16*t2 + g4 + r) * ASTRB + C0 + 16*j + c] = (__bf16)acc[t2][j][r];
}

// C (2x2 tiles) -> single-bf16 TRANSPOSED vT[d][m]
__device__ __forceinline__ void writeC_vt(const f32x4 (&acc)[2][2],
                                          __bf16* __restrict__ hi, int lane, int wave)
{
    const int R0 = (wave >> 2) << 5;   // m rows
    const int C0 = (wave & 3) << 5;    // d cols
    const int c = lane & 15, g4 = (lane >> 4) << 2;
    #pragma unroll
    for (int t2 = 0; t2 < 2; ++t2)
    #pragma unroll
    for (int j = 0; j < 2; ++j)
    #pragma unroll
    for (int r = 0; r < 4; ++r) {
        int m = R0 + 16*t2 + g4 + r, d = C0 + 16*j + c;
        hi[d * VSTR + m] = (__bf16)acc[t2][j][r];
    }
}

// C (2x2 tiles) -> f32 scratch [64][STR]
__device__ __forceinline__ void writeC_f32(const f32x4 (&acc)[2][2],
                                           float* __restrict__ dst, int lane, int wave)
{
    const int R0 = (wave >> 2) << 5;
    const int C0 = (wave & 3) << 5;
    const int c = lane & 15, g4 = (lane >> 4) << 2;
    #pragma unroll
    for (int t2 = 0; t2 < 2; ++t2)
    #pragma unroll
    for (int j = 0; j < 2; ++j)
    #pragma unroll
    for (int r = 0; r < 4; ++r)
        dst[(R0 + 16*t2 + g4 + r) * STR + C0 + 16*j + c] = acc[t2][j][r];
}

// Pre-split weights into bf16 hi/lo, packed in MFMA B-fragment order.
// Slot layout: wpack[(kind*3 + l)*32768]: [0,16384)=hi frags, [16384,32768)=lo.
// (lo plane kept for layout compatibility; unused by the kernel now.)
template<bool BF16>
__global__ __launch_bounds__(256)
void prep_w(const void* __restrict__ Wq, const void* __restrict__ Wk,
            const void* __restrict__ Wv, const void* __restrict__ Wo,
            const void* __restrict__ Wf, unsigned short* __restrict__ wpack)
{
    {
        const unsigned int* w = (const unsigned int*)Wq;
        bool isbf = true;
        #pragma unroll
        for (int i = 0; i < 16; ++i) {
            unsigned int e = (w[i] >> 7) & 0xFFu;
            isbf = isbf && (e >= 0x60u && e <= 0x7Eu);
        }
        if (isbf != BF16) return;
    }
    const int mat  = blockIdx.x;            // 0..14 = kind*3 + l
    const int kind = mat / 3, l = mat % 3;
    const void* src = (kind == 0) ? Wq : (kind == 1) ? Wk : (kind == 2) ? Wv
                    : (kind == 3) ? Wo : Wf;
    unsigned short* dh = wpack + (size_t)mat * 32768;
    unsigned short* dl = dh + 16384;
    for (int f = threadIdx.x; f < 16384; f += 256) {
        int e    = f & 7;
        int lane = (f >> 3) & 63;
        int tj   = (f >> 9) & 7;
        int kc   = f >> 12;
        int row  = kc * 32 + ((lane >> 4) << 3) + e;
        int col  = tj * 16 + (lane & 15);
        float x  = ldT<BF16>(src, (l * NF + row) * NF + col);
        unsigned short hi = f2bf(x);
        unsigned short lo = f2bf(x - bf2f(hi));
        dh[f] = hi; dl[f] = lo;
    }
}

// a 8704 + q 8704 + k 8704 + vt 9216 + P 8192 = 43520 bf16 + tail
static constexpr size_t SMEM_BYTES =
    (size_t)43520 * 2 + (256 + 48) * 4 + 16;   // 88272 B

template<bool BF16>
__global__ __launch_bounds__(NTH, 1)
void gnn_fused(const void* __restrict__ coords,
               const int* __restrict__ species,
               const unsigned char* __restrict__ maskraw,
               const void* __restrict__ embed,
               const void* __restrict__ Wq,          // dtype signature only
               const void* __restrict__ We,
               const void* __restrict__ bfb,
               const unsigned short* __restrict__ wpack,
               void* __restrict__ out)
{
    // ---- dtype signature check (block-uniform; wrong instantiation exits) ----
    {
        const unsigned int* w = (const unsigned int*)Wq;
        bool isbf = true;
        #pragma unroll
        for (int i = 0; i < 16; ++i) {
            unsigned int e = (w[i] >> 7) & 0xFFu;
            isbf = isbf && (e >= 0x60u && e <= 0x7Eu);
        }
        if (isbf != BF16) return;
    }

    extern __shared__ __bf16 sm[];
    __bf16* a_hi  = sm;                                 // [64][136] hn/msg
    __bf16* q_hi  = sm + 8704;                          // [64][136] q
    __bf16* k_hi  = sm + 17408;                         // [64][136] k
    __bf16* vt_hi = sm + 26112;                         // [128][72] v transposed
    __bf16* p_hi  = sm + 35328;                         // 8 waves x 2KB swz
    float*  scratch = (float*)k_hi;                     // spans k+vt: 35840B >= 33792B
    float*  tailf = (float*)(sm + 43520);
    float*  cs   = tailf;                               // 64*4 coords
    float*  wel  = cs + 256;                            // 48 We (f32)
    int*    lenp = (int*)(wel + 48);

    const int t    = threadIdx.x;
    const int b    = blockIdx.x;
    const int fq   = t & 31;
    const int r0   = (t >> 5) * 4;
    const int lane = t & 63;
    const int wave = t >> 6;
    const int c    = lane & 15;
    const int g    = lane >> 4;
    const int g4   = g << 2;
    const int hd   = wave >> 2;          // attention head of this wave
    const int wb   = (wave & 3) << 4;    // attention row base of this wave

    // ---- init: coords, We, mask length ----
    if (t < 64) {
        cs[t * 4 + 0] = ldT<BF16>(coords, (b * NATOM + t) * 3 + 0);
        cs[t * 4 + 1] = ldT<BF16>(coords, (b * NATOM + t) * 3 + 1);
        cs[t * 4 + 2] = ldT<BF16>(coords, (b * NATOM + t) * 3 + 2);
    }
    if (t >= 64 && t < 64 + 42) wel[t - 64] = ldT<BF16>(We, t - 64);
    if (t < 64) {
        unsigned int w0 = *(const unsigned int*)maskraw;
        bool f;
        if (w0 == 1u)               f = ((const int*)maskraw)[b * NATOM + t] != 0;
        else if (w0 == 0x01010101u) f = maskraw[b * NATOM + t] != 0;
        else if (w0 == 0x3F800000u) f = ((const float*)maskraw)[b * NATOM + t] != 0.f;
        else                        f = ((const unsigned short*)maskraw)[b * NATOM + t] != 0;
        unsigned long long bal = __ballot(f);
        if (t == 0) *lenp = (int)__popcll(bal);
    }

    // ---- h0 = embed[species-1] ----
    float h[4][4];
    #pragma unroll
    for (int i = 0; i < 4; ++i) {
        int sp = species[b * NATOM + r0 + i];
        float4 ev = ld4T<BF16>(embed, (sp - 1) * NF + fq * 4);
        h[i][0] = ev.x; h[i][1] = ev.y; h[i][2] = ev.z; h[i][3] = ev.w;
    }
    __syncthreads();
    const int len = *lenp;
    #pragma unroll
    for (int i = 0; i < 4; ++i)
        if (r0 + i >= len) { h[i][0]=0.f; h[i][1]=0.f; h[i][2]=0.f; h[i][3]=0.f; }

    // ---- layer-invariant edge cache: d and exp(-d) per pair (32 regs) ----
    float pdc[4][4], pec[4][4];
    {
        float cnx[4], cny[4], cnz[4];
        #pragma unroll
        for (int r = 0; r < 4; ++r) {
            int n = wb + g4 + r;
            cnx[r] = cs[n*4]; cny[r] = cs[n*4+1]; cnz[r] = cs[n*4+2];
        }
        #pragma unroll
        for (int jt = 0; jt < 4; ++jt) {
            int mc = jt * 16 + c;
            float cmx = cs[mc*4], cmy = cs[mc*4+1], cmz = cs[mc*4+2];
            #pragma unroll
            for (int r = 0; r < 4; ++r) {
                float dx = cnx[r]-cmx, dy = cny[r]-cmy, dz = cnz[r]-cmz;
                float d = fast_sqrt(dx*dx + dy*dy + dz*dz + 1e-12f);
                pdc[jt][r] = d;
                pec[jt][r] = fast_exp(-d);
            }
        }
    }

    float mu[4], rs[4];
    for (int l = 0; l < NLAYER; ++l) {
        // hn = LN(h) -> single-bf16 A tile
        ln_stats(h, mu, rs);
        write_a(h, mu, rs, a_hi, r0, fq);
        __syncthreads();                                        // B1: a ready

        // k, vT, q: fused dense, A-frags shared, 1-term each
        {
            f32x4 kacc[2][2], vacc[2][2], qacc[2][2];
            mfma_dense3(a_hi,
                        (const __bf16*)wpack + (size_t)(3 + l) * 32768,
                        (const __bf16*)wpack + (size_t)(6 + l) * 32768,
                        (const __bf16*)wpack + (size_t)(0 + l) * 32768,
                        kacc, vacc, qacc, lane, wave);
            writeC_rm(kacc, k_hi, lane, wave);
            writeC_vt(vacc, vt_hi, lane, wave);
            writeC_rm(qacc, q_hi, lane, wave);
        }
        __syncthreads();                                        // B2: k/vT/q visible

        // ---- logits = (q @ k^T)/8 + bias (NT: k row-major IS B-frag), 1-term ----
        f32x4 lacc[4];
        #pragma unroll
        for (int jt = 0; jt < 4; ++jt) lacc[jt] = (f32x4){0.f,0.f,0.f,0.f};
        #pragma unroll
        for (int kc = 0; kc < 2; ++kc) {
            const int qo = (wb + c) * ASTRB + hd * 64 + kc * 32 + (g << 3);
            bf16x8 qh = *(const bf16x8*)&q_hi[qo];
            #pragma unroll
            for (int jt = 0; jt < 4; ++jt) {
                const int ko = (jt * 16 + c) * ASTRB + hd * 64 + kc * 32 + (g << 3);
                bf16x8 kh = *(const bf16x8*)&k_hi[ko];
                lacc[jt] = __builtin_amdgcn_mfma_f32_16x16x32_bf16(qh, kh, lacc[jt], 0, 0, 0);
            }
        }

        // ---- edge bias (cached d/exp) + masked softmax ----
        float we_[7];
        #pragma unroll
        for (int e = 0; e < 7; ++e) we_[e] = wel[l * 14 + e * 2 + hd];
        float cnx[4], cny[4], cnz[4];
        #pragma unroll
        for (int r = 0; r < 4; ++r) {
            int n = wb + g4 + r;
            cnx[r] = cs[n*4]; cny[r] = cs[n*4+1]; cnz[r] = cs[n*4+2];
        }
        float lg[4][4];
        #pragma unroll
        for (int jt = 0; jt < 4; ++jt) {
            int mc = jt * 16 + c;
            float cmx = cs[mc*4], cmy = cs[mc*4+1], cmz = cs[mc*4+2];
            #pragma unroll
            for (int r = 0; r < 4; ++r) {
                float dx = cnx[r]-cmx, dy = cny[r]-cmy, dz = cnz[r]-cmz;
                float et = pec[jt][r];
                float s1 = fast_rcp(1.f + 7.38905609893065f   * et);
                float s2 = fast_rcp(1.f + 54.598150033144236f * et);
                float s3 = fast_rcp(1.f + 403.4287934927351f  * et);
                lg[jt][r] = lacc[jt][r] * 0.125f
                          + dx*we_[0] + dy*we_[1] + dz*we_[2]
                          + pdc[jt][r]*we_[3]
                          + s1*we_[4] + s2*we_[5] + s3*we_[6];
            }
        }
        float mx[4] = {-3e38f, -3e38f, -3e38f, -3e38f};
        #pragma unroll
        for (int jt = 0; jt < 4; ++jt)
            if (jt * 16 + c < len) {
                #pragma unroll
                for (int r = 0; r < 4; ++r) mx[r] = fmaxf(mx[r], lg[jt][r]);
            }
        #pragma unroll
        for (int r = 0; r < 4; ++r) {
            mx[r] = fmaxf(mx[r], __shfl_xor(mx[r], 1));
            mx[r] = fmaxf(mx[r], __shfl_xor(mx[r], 2));
            mx[r] = fmaxf(mx[r], __shfl_xor(mx[r], 4));
            mx[r] = fmaxf(mx[r], __shfl_xor(mx[r], 8));
        }
        float sv[4] = {0.f, 0.f, 0.f, 0.f};
        #pragma unroll
        for (int jt = 0; jt < 4; ++jt) {
            bool vm = (jt * 16 + c) < len;
            #pragma unroll
            for (int r = 0; r < 4; ++r) {
                float e = vm ? fast_exp(lg[jt][r] - mx[r]) : 0.f;
                lg[jt][r] = e; sv[r] += e;
            }
        }
        #pragma unroll
        for (int r = 0; r < 4; ++r) {
            sv[r] += __shfl_xor(sv[r], 1);
            sv[r] += __shfl_xor(sv[r], 2);
            sv[r] += __shfl_xor(sv[r], 4);
            sv[r] += __shfl_xor(sv[r], 8);
        }
        float inv[4];
        #pragma unroll
        for (int r = 0; r < 4; ++r)
            inv[r] = (wb + g4 + r < len) ? fast_rcp(sv[r]) : 0.f;

        // ---- P stage: single-bf16, own 2KB swizzled slab per wave ----
        // elem (x=0..15 q-row, mm=0..63 k-idx): byte = x*128 + ((mm*2) ^ ((x&7)<<4))
        {
            char* pw = (char*)p_hi + wave * 2048;
            #pragma unroll
            for (int jt = 0; jt < 4; ++jt)
                #pragma unroll
                for (int r = 0; r < 4; ++r) {
                    int x = g4 + r, mm = jt * 16 + c;
                    *(__bf16*)(pw + x * 128 + ((mm * 2) ^ ((x & 7) << 4))) =
                        (__bf16)(lg[jt][r] * inv[r]);
                }
        }
        // no barrier: P write->read is same-wave (lgkmcnt-ordered)

        // ---- msg = P @ V (1-term) ----
        f32x4 macc[4];
        #pragma unroll
        for (int jt = 0; jt < 4; ++jt) macc[jt] = (f32x4){0.f,0.f,0.f,0.f};
        #pragma unroll
        for (int kc = 0; kc < 2; ++kc) {
            const char* pw = (const char*)p_hi + wave * 2048;
            const int m0 = kc * 32 + (g << 3);
            bf16x8 ph = *(const bf16x8*)(pw + c * 128 + ((m0 * 2) ^ ((c & 7) << 4)));
            #pragma unroll
            for (int jt = 0; jt < 4; ++jt) {
                const int vo = (hd * 64 + jt * 16 + c) * VSTR + kc * 32 + (g << 3);
                bf16x8 vh = *(const bf16x8*)&vt_hi[vo];
                macc[jt] = __builtin_amdgcn_mfma_f32_16x16x32_bf16(ph, vh, macc[jt], 0, 0, 0);
            }
        }
        // msg -> a-region single-bf16 (a dead: all a-readers finished pre-B2)
        #pragma unroll
        for (int jt = 0; jt < 4; ++jt)
            #pragma unroll
            for (int r = 0; r < 4; ++r) {
                int idx = (wb + g4 + r) * ASTRB + hd * 64 + jt * 16 + c;
                a_hi[idx] = (__bf16)macc[jt][r];
            }
        __syncthreads();                                        // B3: msg visible; k/vt/P dead

        // h += msg @ Wo (1-term; f32 scratch overlays dead k + vt region)
        {
            f32x4 oacc[2][2];
            mfma_dense(a_hi, (const __bf16*)wpack + (size_t)(9 + l) * 32768, oacc, lane, wave);
            writeC_f32(oacc, scratch, lane, wave);
        }
        __syncthreads();                                        // B4: scratch visible
        #pragma unroll
        for (int i = 0; i < 4; ++i) {
            float4 ov = *(const float4*)&scratch[(r0 + i) * STR + fq * 4];
            h[i][0] += ov.x; h[i][1] += ov.y; h[i][2] += ov.z; h[i][3] += ov.w;
        }

        // h += tanh(LN(h) @ Wf + bf)  (1-term)
        ln_stats(h, mu, rs);
        write_a(h, mu, rs, a_hi, r0, fq);     // Wo a-reads drained at B4
        __syncthreads();                                        // B5: a ready
        {
            f32x4 facc[2][2];
            mfma_dense(a_hi, (const __bf16*)wpack + (size_t)(12 + l) * 32768, facc, lane, wave);
            writeC_f32(facc, scratch, lane, wave);   // h-update scratch reads drained at B5
        }
        __syncthreads();                                        // B6: scratch visible
        {
            float4 bv = ld4T<BF16>(bfb, l * NF + fq * 4);
            #pragma unroll
            for (int i = 0; i < 4; ++i) {
                float z0 = scratch[(r0 + i) * STR + fq * 4 + 0] + bv.x;
                float z1 = scratch[(r0 + i) * STR + fq * 4 + 1] + bv.y;
                float z2 = scratch[(r0 + i) * STR + fq * 4 + 2] + bv.z;
                float z3 = scratch[(r0 + i) * STR + fq * 4 + 3] + bv.w;
                // tanh(z) = 1 - 2/(e^{2z}+1)
                h[i][0] += 1.f - 2.f * fast_rcp(fast_exp(2.f*z0) + 1.f);
                h[i][1] += 1.f - 2.f * fast_rcp(fast_exp(2.f*z1) + 1.f);
                h[i][2] += 1.f - 2.f * fast_rcp(fast_exp(2.f*z2) + 1.f);
                h[i][3] += 1.f - 2.f * fast_rcp(fast_exp(2.f*z3) + 1.f);
            }
        }
        // h *= mask
        #pragma unroll
        for (int i = 0; i < 4; ++i)
            if (r0 + i >= len) { h[i][0]=0.f; h[i][1]=0.f; h[i][2]=0.f; h[i][3]=0.f; }
        // next-layer write_a is safe: Wf a-reads drained at B6; tanh reads
        // scratch (k region), not a; next B1 orders write_a vs k-writes.
    }

    // out = LN(h) in output dtype
    ln_stats(h, mu, rs);
    #pragma unroll
    for (int i = 0; i < 4; ++i) {
        int idx = b * NATOM * NF + (r0 + i) * NF + fq * 4;
        float o0 = (h[i][0]-mu[i])*rs[i], o1 = (h[i][1]-mu[i])*rs[i];
        float o2 = (h[i][2]-mu[i])*rs[i], o3 = (h[i][3]-mu[i])*rs[i];
        if constexpr (BF16) {
            ushort4 o;
            o.x = bfbits(o0); o.y = bfbits(o1); o.z = bfbits(o2); o.w = bfbits(o3);
            *(ushort4*)((unsigned short*)out + idx) = o;
        } else {
            *(float4*)((float*)out + idx) = make_float4(o0, o1, o2, o3);
        }
    }
}

extern "C" void kernel_launch(void* const* d_in, const int* in_sizes, int n_in,
                              void* d_out, int out_size, void* d_ws, size_t ws_size,
                              hipStream_t stream) {
    const void*           coords  = d_in[0];
    const int*            species = (const int*)d_in[1];
    const unsigned char*  maskraw = (const unsigned char*)d_in[2];
    const void*           embed   = d_in[3];
    const void*           Wq      = d_in[4];
    const void*           Wk      = d_in[5];
    const void*           Wv      = d_in[6];
    const void*           Wo      = d_in[7];
    const void*           We      = d_in[8];
    const void*           Wf      = d_in[9];
    const void*           bfb     = d_in[10];

    unsigned short* wpack = (unsigned short*)d_ws;   // 15 * 32768 ushorts = 960 KB

    (void)hipFuncSetAttribute((const void*)gnn_fused<true>,
                              hipFuncAttributeMaxDynamicSharedMemorySize,
                              (int)SMEM_BYTES);
    (void)hipFuncSetAttribute((const void*)gnn_fused<false>,
                              hipFuncAttributeMaxDynamicSharedMemorySize,
                              (int)SMEM_BYTES);

    prep_w<true ><<<dim3(15), dim3(256), 0, stream>>>(Wq, Wk, Wv, Wo, Wf, wpack);
    prep_w<false><<<dim3(15), dim3(256), 0, stream>>>(Wq, Wk, Wv, Wo, Wf, wpack);

    gnn_fused<true ><<<dim3(NBATCH), dim3(NTH), SMEM_BYTES, stream>>>(
        coords, species, maskraw, embed, Wq, We, bfb, wpack, d_out);
    gnn_fused<false><<<dim3(NBATCH), dim3(NTH), SMEM_BYTES, stream>>>(
        coords, species, maskraw, embed, Wq, We, bfb, wpack, d_out);
}